// Round 9
// baseline (751.912 us; speedup 1.0000x reference)
//
#include <hip/hip_runtime.h>
#include <hip/hip_cooperative_groups.h>

// SAGE_Net: 2-layer GraphSAGE, N=100k, E=1.6M, 128->128->64, fp32.
// R18: dispatch-count collapse. Kernel sums ~190us vs total 318.7 -> ~120us
// of inter-dispatch overhead across 8 dispatches (memset + 7 kernels).
// New k_build (cooperative, 1024 blocks): prep -> sync -> bcount -> sync ->
// block0 scan -> sync -> scatter (reuses stage-B LDS hist; one ei pass
// dropped) -> sync -> bfinal. Memset folded in. k_fused / k_agg_out are
// byte-identical to R17 (measured 99us / ~unchanged). 8 -> 3 dispatches.

namespace cg = cooperative_groups;

typedef unsigned int uint32;
typedef short bf16x8 __attribute__((ext_vector_type(8)));
typedef float f32x16 __attribute__((ext_vector_type(16)));
typedef float f32x2 __attribute__((ext_vector_type(2)));

#define PSTR 264  // LDS plane stride in shorts (32*8 + 8 pad; 528B)

__device__ __forceinline__ uint32 pack_bf16_rne(float a, float b) {
    uint32 ua = __float_as_uint(a);
    uint32 ub = __float_as_uint(b);
    uint32 ra = (ua + 0x7fffu + ((ua >> 16) & 1u)) >> 16;
    uint32 rb = (ub + 0x7fffu + ((ub >> 16) & 1u)) >> 16;
    return ra | (rb << 16);
}
__device__ __forceinline__ float bf_lo(uint32 v) { return __uint_as_float(v << 16); }

__device__ __forceinline__ short rne16(float v, float* back) {
    uint32 u = __float_as_uint(v);
    uint32 r = (u + 0x7fffu + ((u >> 16) & 1u)) >> 16;
    *back = __uint_as_float(r << 16);
    return (short)r;
}

// ---- cooperative build: prep + CSR in ONE kernel (4 grid syncs) ----
// Grid: 1024 blocks x 256. __launch_bounds__(256,4) -> <=128 VGPR ->
// >=4 blocks/CU co-resident (LDS 7KB) -> 1024 blocks always fit.

__global__ __launch_bounds__(256, 4) void k_build(
        const float* __restrict__ x, uint32* __restrict__ xb, long n4,
        const float* __restrict__ W1l, const float* __restrict__ W1r,
        const float* __restrict__ W2l, const float* __restrict__ W2r,
        short* __restrict__ W1pH, short* __restrict__ W1pL,
        short* __restrict__ W2pH, short* __restrict__ W2pL,
        const int* __restrict__ ei, int E, int NB,
        int* __restrict__ bcnt, int* __restrict__ boff, int* __restrict__ bcur,
        uint32* __restrict__ eb, int* __restrict__ row_ptr,
        int* __restrict__ col, int N) {
    cg::grid_group grid = cg::this_grid();
    __shared__ int hist[512];   // lives B -> D (block stays resident)
    __shared__ int base[512];   // stage C scan scratch, then stage D bases
    __shared__ int deg[256];
    __shared__ int scn[256];
    __shared__ int cur[256];
    int t = threadIdx.x;
    int b = blockIdx.x;
    int nb = gridDim.x;
    long gstride = (long)nb * 256;

    // ---- stage 0: prep (grid-stride) + zero bcnt ----
    long total = n4 + 32768 + 16384;
    for (long i = (long)b * 256 + t; i < total; i += gstride) {
        float back;
        if (i < n4) {
            float4 v = ((const float4*)x)[i];
            short h0 = rne16(v.x, &back);
            short h1 = rne16(v.y, &back);
            short h2 = rne16(v.z, &back);
            short h3 = rne16(v.w, &back);
            uint2 o;
            o.x = (uint32)(unsigned short)h0 | ((uint32)(unsigned short)h1 << 16);
            o.y = (uint32)(unsigned short)h2 | ((uint32)(unsigned short)h3 << 16);
            ((uint2*)xb)[i] = o;
            continue;
        }
        int i2 = (int)(i - n4);
        if (i2 < 32768) {
            int j = i2 >> 8, k = i2 & 255;
            float v = (k < 128) ? W1l[j * 128 + k] : W1r[j * 128 + k - 128];
            float hb;
            short hs = rne16(v, &hb);
            short ls = rne16(v - hb, &back);
            int idx = (k >> 3) * 1024 + j * 8 + (k & 7);
            W1pH[idx] = hs;
            W1pL[idx] = ls;
        } else {
            int i3 = i2 - 32768;
            int j = i3 >> 7, k = i3 & 127;
            float v = (j < 64) ? W2l[j * 128 + k] : W2r[(j - 64) * 128 + k];
            float hb;
            short hs = rne16(v, &hb);
            short ls = rne16(v - hb, &back);
            int idx = (k >> 3) * 1024 + j * 8 + (k & 7);
            W2pH[idx] = hs;
            W2pL[idx] = ls;
        }
    }
    for (int i = b * 256 + t; i <= NB; i += nb * 256) bcnt[i] = 0;
    grid.sync();

    // ---- stage B: bcount (per-block LDS hist, kept for stage D) ----
    hist[t] = 0;
    hist[t + 256] = 0;
    __syncthreads();
    for (long e = (long)b * 256 + t; e < E; e += gstride)
        atomicAdd(&hist[ei[E + e] >> 8], 1);
    __syncthreads();
    for (int i = t; i < NB; i += 256) {
        int c = hist[i];
        if (c) atomicAdd(&bcnt[i], c);
    }
    grid.sync();

    // ---- stage C: block 0 scans bcnt -> boff/bcur; row_ptr[N], boff[NB] ----
    if (b == 0) {
        int c0 = (t < NB) ? bcnt[t] : 0;
        int c1 = (t + 256 < NB) ? bcnt[t + 256] : 0;
        base[t] = c0;
        base[t + 256] = c1;
        __syncthreads();
        for (int o = 1; o < 512; o <<= 1) {
            int a0 = (t >= o) ? base[t - o] : 0;
            int a1 = (t + 256 >= o) ? base[t + 256 - o] : 0;
            __syncthreads();
            base[t] += a0;
            base[t + 256] += a1;
            __syncthreads();
        }
        if (t < NB) { boff[t] = base[t] - c0; bcur[t] = base[t] - c0; }
        if (t + 256 < NB) {
            boff[t + 256] = base[t + 256] - c1;
            bcur[t + 256] = base[t + 256] - c1;
        }
        if (t == 0) { boff[NB] = E; row_ptr[N] = E; }
    }
    grid.sync();

    // ---- stage D: scatter, reusing stage-B hist (no recount pass) ----
    for (int i = t; i < NB; i += 256) {
        int c = hist[i];
        base[i] = c ? atomicAdd(&bcur[i], c) : 0;
        hist[i] = 0;
    }
    __syncthreads();
    for (long e = (long)b * 256 + t; e < E; e += gstride) {
        int d = ei[E + e];
        int bk = d >> 8;
        int r = atomicAdd(&hist[bk], 1);
        eb[base[bk] + r] = ((uint32)(d & 255) << 24) | (uint32)ei[e];
    }
    grid.sync();

    // ---- stage E: per-bucket CSR finalize ----
    for (int bb = b; bb < NB; bb += nb) {
        int beg = boff[bb], end = boff[bb + 1];
        deg[t] = 0;
        __syncthreads();
        for (int e = beg + t; e < end; e += 256)
            atomicAdd(&deg[eb[e] >> 24], 1);
        __syncthreads();
        int v = deg[t];
        scn[t] = v;
        __syncthreads();
        for (int o = 1; o < 256; o <<= 1) {
            int u = (t >= o) ? scn[t - o] : 0;
            __syncthreads();
            scn[t] += u;
            __syncthreads();
        }
        int ex = scn[t] - v;
        int node = bb * 256 + t;
        if (node < N) row_ptr[node] = beg + ex;
        cur[t] = ex;
        __syncthreads();
        for (int e = beg + t; e < end; e += 256) {
            uint32 u = eb[e];
            int r = atomicAdd(&cur[u >> 24], 1);
            col[beg + r] = (int)(u & 0xFFFFFFu);
        }
        __syncthreads();
    }
}

// ---- fused gather-mean + 2x MFMA GEMM (byte-identical to R17) ----

__global__ __launch_bounds__(256, 4) void k_fused(
        const int* __restrict__ rp, const int* __restrict__ col,
        const uint32* __restrict__ xb,
        const short* __restrict__ W1pH, const short* __restrict__ W1pL,
        const short* __restrict__ W2pH, const short* __restrict__ W2pL,
        const float* __restrict__ b1, const float* __restrict__ b2,
        unsigned short* __restrict__ hl, float* __restrict__ hr, int N) {
    __shared__ short smH[16 * PSTR];  // mean hi planes; reused for h hi
    __shared__ short smL[16 * PSTR];  // mean lo planes; reused for h lo
    int t = threadIdx.x;
    int w = t >> 6, lane = t & 63;
    int node0 = blockIdx.x * 32;

    // phase A: gather-mean for 8 nodes/wave. rp prefetched via one load.
    int base = node0 + 8 * w;
    int rpi = base + lane;
    if (rpi > N) rpi = N;
    int rpv = rp[rpi];

#define ACC1(a) { s += (f32x2){bf_lo(a), __uint_as_float(a)}; }

    for (int i = 0; i < 8; i++) {
        int lr = 8 * w + i;
        int beg = __builtin_amdgcn_readfirstlane(__shfl(rpv, i));
        int end = __builtin_amdgcn_readfirstlane(__shfl(rpv, i + 1));
        f32x2 s = (f32x2){0.f, 0.f};
        int e = beg;
        for (; e + 8 <= end; e += 8) {
            int c0 = col[e + 0], c1 = col[e + 1], c2 = col[e + 2], c3 = col[e + 3];
            int c4 = col[e + 4], c5 = col[e + 5], c6 = col[e + 6], c7 = col[e + 7];
            uint32 a0 = xb[(size_t)c0 * 64 + lane];
            uint32 a1 = xb[(size_t)c1 * 64 + lane];
            uint32 a2 = xb[(size_t)c2 * 64 + lane];
            uint32 a3 = xb[(size_t)c3 * 64 + lane];
            uint32 a4 = xb[(size_t)c4 * 64 + lane];
            uint32 a5 = xb[(size_t)c5 * 64 + lane];
            uint32 a6 = xb[(size_t)c6 * 64 + lane];
            uint32 a7 = xb[(size_t)c7 * 64 + lane];
            ACC1(a0); ACC1(a1); ACC1(a2); ACC1(a3);
            ACC1(a4); ACC1(a5); ACC1(a6); ACC1(a7);
        }
        for (; e + 4 <= end; e += 4) {
            int c0 = col[e + 0], c1 = col[e + 1], c2 = col[e + 2], c3 = col[e + 3];
            uint32 a0 = xb[(size_t)c0 * 64 + lane];
            uint32 a1 = xb[(size_t)c1 * 64 + lane];
            uint32 a2 = xb[(size_t)c2 * 64 + lane];
            uint32 a3 = xb[(size_t)c3 * 64 + lane];
            ACC1(a0); ACC1(a1); ACC1(a2); ACC1(a3);
        }
        for (; e < end; e++) {
            uint32 a0 = xb[(size_t)col[e] * 64 + lane];
            ACC1(a0);
        }
        // epilogue: lane l -> plane l>>2, node lr, shorts 2(l&3)..+1
        float inv = 1.0f / (float)max(end - beg, 1);
        float m0 = s.x * inv, m1 = s.y * inv;
        float b_;
        short h0 = rne16(m0, &b_);
        float bk0 = b_;
        short l0 = rne16(m0 - bk0, &b_);
        short h1 = rne16(m1, &b_);
        float bk1 = b_;
        short l1 = rne16(m1 - bk1, &b_);
        uint32 H = (uint32)(unsigned short)h0 | ((uint32)(unsigned short)h1 << 16);
        uint32 L = (uint32)(unsigned short)l0 | ((uint32)(unsigned short)l1 << 16);
        int idx = (lane >> 2) * PSTR + lr * 8 + 2 * (lane & 3);
        *(uint32*)&smH[idx] = H;
        *(uint32*)&smL[idx] = L;
    }
#undef ACC1
    __syncthreads();

    // phase B: GEMM1 (mean hi/lo from LDS + x hi direct from xb), tile jt=w
    int m = lane & 31, hh = lane >> 5;
    int mynode = node0 + m;
    const short* xbs = (const short*)xb;  // row = 128 shorts (feature order)
    f32x16 acc;
#pragma unroll
    for (int r = 0; r < 16; r++) acc[r] = 0.f;
#pragma unroll
    for (int kc = 0; kc < 8; kc++) {
        int c = 2 * kc + hh;
        bf16x8 bH = *(const bf16x8*)&smH[c * PSTR + m * 8];
        bf16x8 bL = *(const bf16x8*)&smL[c * PSTR + m * 8];
        bf16x8 xH = *(const bf16x8*)(xbs + (size_t)mynode * 128 + c * 8);
        bf16x8 aH1 = *(const bf16x8*)(W1pH + c * 1024 + (32 * w + m) * 8);
        bf16x8 aL1 = *(const bf16x8*)(W1pL + c * 1024 + (32 * w + m) * 8);
        bf16x8 aH2 = *(const bf16x8*)(W1pH + (16 + c) * 1024 + (32 * w + m) * 8);
        bf16x8 aL2 = *(const bf16x8*)(W1pL + (16 + c) * 1024 + (32 * w + m) * 8);
        acc = __builtin_amdgcn_mfma_f32_32x32x16_bf16(aH1, bH, acc, 0, 0, 0);
        acc = __builtin_amdgcn_mfma_f32_32x32x16_bf16(aL1, bH, acc, 0, 0, 0);
        acc = __builtin_amdgcn_mfma_f32_32x32x16_bf16(aH1, bL, acc, 0, 0, 0);
        acc = __builtin_amdgcn_mfma_f32_32x32x16_bf16(aH2, xH, acc, 0, 0, 0);
        acc = __builtin_amdgcn_mfma_f32_32x32x16_bf16(aL2, xH, acc, 0, 0, 0);
    }

    // epilogue 1: relu + b1 -> h (hi/lo) in regs
    uint2 oh[4], ol[4];
#pragma unroll
    for (int rg = 0; rg < 4; rg++) {
        int j0 = 32 * w + 8 * rg + 4 * hh;
        float4 bv = *(const float4*)(b1 + j0);
        float bb[4] = {bv.x, bv.y, bv.z, bv.w};
        short hs[4], ls[4];
#pragma unroll
        for (int q = 0; q < 4; q++) {
            float v = fmaxf(acc[4 * rg + q] + bb[q], 0.f);
            float back;
            hs[q] = rne16(v, &back);
            ls[q] = rne16(v - back, &back);
        }
        oh[rg].x = (uint32)(unsigned short)hs[0] | ((uint32)(unsigned short)hs[1] << 16);
        oh[rg].y = (uint32)(unsigned short)hs[2] | ((uint32)(unsigned short)hs[3] << 16);
        ol[rg].x = (uint32)(unsigned short)ls[0] | ((uint32)(unsigned short)ls[1] << 16);
        ol[rg].y = (uint32)(unsigned short)ls[2] | ((uint32)(unsigned short)ls[3] << 16);
    }
    __syncthreads();  // all waves done reading mean planes
#pragma unroll
    for (int rg = 0; rg < 4; rg++) {
        int idx = (4 * w + rg) * PSTR + m * 8 + 4 * hh;  // plane j>>3 = 4w+rg
        *(uint2*)&smH[idx] = oh[rg];
        *(uint2*)&smL[idx] = ol[rg];
    }
    __syncthreads();

    // GEMM2: B-fragments from LDS h planes, tile jt=w
#pragma unroll
    for (int r = 0; r < 16; r++) acc[r] = 0.f;
#pragma unroll
    for (int kc = 0; kc < 8; kc++) {
        int c = 2 * kc + hh;
        bf16x8 bH = *(const bf16x8*)&smH[c * PSTR + m * 8];
        bf16x8 bL = *(const bf16x8*)&smL[c * PSTR + m * 8];
        bf16x8 aH = *(const bf16x8*)(W2pH + c * 1024 + (32 * w + m) * 8);
        bf16x8 aL = *(const bf16x8*)(W2pL + c * 1024 + (32 * w + m) * 8);
        acc = __builtin_amdgcn_mfma_f32_32x32x16_bf16(aH, bH, acc, 0, 0, 0);
        acc = __builtin_amdgcn_mfma_f32_32x32x16_bf16(aL, bH, acc, 0, 0, 0);
        acc = __builtin_amdgcn_mfma_f32_32x32x16_bf16(aH, bL, acc, 0, 0, 0);
    }
    if (mynode >= N) return;
    if (w < 2) {
        // waves 0,1: cols 0..63 = h @ W2l^T -> hl (bf16)
#pragma unroll
        for (int rg = 0; rg < 4; rg++) {
            int j0 = 32 * w + 8 * rg + 4 * hh;
            uint2 o;
            o.x = pack_bf16_rne(acc[4 * rg + 0], acc[4 * rg + 1]);
            o.y = pack_bf16_rne(acc[4 * rg + 2], acc[4 * rg + 3]);
            *(uint2*)&hl[(size_t)mynode * 64 + j0] = o;
        }
    } else {
        // waves 2,3: cols 64..127 = h @ W2r^T + b2 -> hr (fp32)
#pragma unroll
        for (int rg = 0; rg < 4; rg++) {
            int j0 = 32 * (w - 2) + 8 * rg + 4 * hh;
            float4 bv = *(const float4*)(b2 + j0);
            float4 o;
            o.x = acc[4 * rg + 0] + bv.x;
            o.y = acc[4 * rg + 1] + bv.y;
            o.z = acc[4 * rg + 2] + bv.z;
            o.w = acc[4 * rg + 3] + bv.w;
            *(float4*)&hr[(size_t)mynode * 64 + j0] = o;
        }
    }
}

// ---- aggregation 2 (byte-identical to R17) ----

__global__ void k_agg_out(const int* __restrict__ rp, const int* __restrict__ col,
                          const unsigned short* __restrict__ hl,
                          const float* __restrict__ hr,
                          float* __restrict__ out, int N) {
    int node = blockIdx.x * 4 + (threadIdx.x >> 6);
    if (node >= N) return;
    node = __builtin_amdgcn_readfirstlane(node);
    int lane = threadIdx.x & 63;
    int beg = rp[node], end = rp[node + 1];
    float s = 0.f;

#define ACCU(a) { s += __uint_as_float((uint32)(a) << 16); }

    int e = beg;
    for (; e + 8 <= end; e += 8) {
        int c0 = col[e + 0], c1 = col[e + 1], c2 = col[e + 2], c3 = col[e + 3];
        int c4 = col[e + 4], c5 = col[e + 5], c6 = col[e + 6], c7 = col[e + 7];
        unsigned short a0 = hl[(size_t)c0 * 64 + lane];
        unsigned short a1 = hl[(size_t)c1 * 64 + lane];
        unsigned short a2 = hl[(size_t)c2 * 64 + lane];
        unsigned short a3 = hl[(size_t)c3 * 64 + lane];
        unsigned short a4 = hl[(size_t)c4 * 64 + lane];
        unsigned short a5 = hl[(size_t)c5 * 64 + lane];
        unsigned short a6 = hl[(size_t)c6 * 64 + lane];
        unsigned short a7 = hl[(size_t)c7 * 64 + lane];
        ACCU(a0); ACCU(a1); ACCU(a2); ACCU(a3);
        ACCU(a4); ACCU(a5); ACCU(a6); ACCU(a7);
    }
    for (; e + 4 <= end; e += 4) {
        int c0 = col[e + 0], c1 = col[e + 1], c2 = col[e + 2], c3 = col[e + 3];
        unsigned short a0 = hl[(size_t)c0 * 64 + lane];
        unsigned short a1 = hl[(size_t)c1 * 64 + lane];
        unsigned short a2 = hl[(size_t)c2 * 64 + lane];
        unsigned short a3 = hl[(size_t)c3 * 64 + lane];
        ACCU(a0); ACCU(a1); ACCU(a2); ACCU(a3);
    }
    for (; e < end; e++) {
        unsigned short a0 = hl[(size_t)col[e] * 64 + lane];
        ACCU(a0);
    }
#undef ACCU
    float inv = 1.0f / (float)max(end - beg, 1);
    out[(size_t)node * 64 + lane] = s * inv + hr[(size_t)node * 64 + lane];
}

extern "C" void kernel_launch(void* const* d_in, const int* in_sizes, int n_in,
                              void* d_out, int out_size, void* d_ws, size_t ws_size,
                              hipStream_t stream) {
    const float* x   = (const float*)d_in[0];
    const float* W1l = (const float*)d_in[1];
    const float* W1r = (const float*)d_in[2];
    const float* b1  = (const float*)d_in[3];
    const float* W2l = (const float*)d_in[4];
    const float* W2r = (const float*)d_in[5];
    const float* b2  = (const float*)d_in[6];
    const int*   ei  = (const int*)d_in[7];
    int N = in_sizes[0] / 128;
    int E = in_sizes[7] / 2;
    int NB = (N + 255) >> 8;   // 391 (block-0 scan assumes <=512)
    int mb = (N + 31) / 32;
    int Np = ((N + 127) / 128) * 128;  // padded node count
    float* out = (float*)d_out;

    char* w = (char*)d_ws;
    size_t off = 0;
    auto alloc = [&](size_t bytes) -> char* {
        char* p = w + off;
        off += (bytes + 255) & ~(size_t)255;
        return p;
    };
    int*   row_ptr = (int*)alloc((size_t)(N + 1) * 4);
    int*   bcnt    = (int*)alloc((size_t)(NB + 1) * 4);
    int*   boff    = (int*)alloc((size_t)(NB + 1) * 4);
    int*   bcur    = (int*)alloc((size_t)(NB + 1) * 4);
    short* W1pH    = (short*)alloc(32768 * 2);
    short* W1pL    = (short*)alloc(32768 * 2);
    short* W2pH    = (short*)alloc(16384 * 2);
    short* W2pL    = (short*)alloc(16384 * 2);
    int*   col     = (int*)alloc((size_t)E * 4);
    uint32* xb     = (uint32*)alloc((size_t)Np * 64 * 4);   // 25.6 MB
    float*  hr     = (float*)alloc((size_t)Np * 64 * 4);    // 25.6 MB
    unsigned short* hl = (unsigned short*)alloc((size_t)N * 64 * 2);  // 12.8 MB
    // alias (lifetime-disjoint): eb dead after k_build; hl written by k_fused
    uint32* eb = (uint32*)hl;

    long n4 = (long)N * 32;

    // cooperative build: 1024 blocks x 256 (>=4 blocks/CU co-resident by
    // launch_bounds(256,4) + 7KB LDS -> always fits on 256 CUs)
    {
        void* args[] = {
            (void*)&x, (void*)&xb, (void*)&n4,
            (void*)&W1l, (void*)&W1r, (void*)&W2l, (void*)&W2r,
            (void*)&W1pH, (void*)&W1pL, (void*)&W2pH, (void*)&W2pL,
            (void*)&ei, (void*)&E, (void*)&NB,
            (void*)&bcnt, (void*)&boff, (void*)&bcur,
            (void*)&eb, (void*)&row_ptr, (void*)&col, (void*)&N
        };
        hipLaunchCooperativeKernel((const void*)k_build, dim3(1024), dim3(256),
                                   args, 0, stream);
    }

    k_fused<<<mb, 256, 0, stream>>>(row_ptr, col, xb, W1pH, W1pL, W2pH, W2pL,
                                    b1, b2, hl, hr, N);
    int ab = (N + 3) / 4;
    k_agg_out<<<ab, 256, 0, stream>>>(row_ptr, col, hl, hr, out, N);
}

// Round 10
// 314.832 us; speedup vs baseline: 2.3883x; 2.3883x over previous
//
#include <hip/hip_runtime.h>

// SAGE_Net: 2-layer GraphSAGE, N=100k, E=1.6M, 128->128->64, fp32.
// R19: R18's cooperative build reverted (grid.sync spins: 519us @ 0.7%
// VALU). R18's accounting exposed k_agg_out ~= 120-130us (never in top-5;
// confirmed via R17 budget) -- the largest kernel. New agg_out: TWO nodes
// per wave (half-wave each), 4 groups x 8 lanes x uint4 row slices, uint4
// col loads -> 4 rows in flight/lane and 2x node throughput at ~40 VGPR.
// k_fused byte-identical to R17 (99us); CSR/prep = R14 form (best).

typedef unsigned int uint32;
typedef short bf16x8 __attribute__((ext_vector_type(8)));
typedef float f32x16 __attribute__((ext_vector_type(16)));
typedef float f32x2 __attribute__((ext_vector_type(2)));

#define PSTR 264  // LDS plane stride in shorts (32*8 + 8 pad; 528B)

__device__ __forceinline__ uint32 pack_bf16_rne(float a, float b) {
    uint32 ua = __float_as_uint(a);
    uint32 ub = __float_as_uint(b);
    uint32 ra = (ua + 0x7fffu + ((ua >> 16) & 1u)) >> 16;
    uint32 rb = (ub + 0x7fffu + ((ub >> 16) & 1u)) >> 16;
    return ra | (rb << 16);
}
__device__ __forceinline__ float bf_lo(uint32 v) { return __uint_as_float(v << 16); }
__device__ __forceinline__ float bf_hi(uint32 v) { return __uint_as_float(v & 0xffff0000u); }

__device__ __forceinline__ short rne16(float v, float* back) {
    uint32 u = __float_as_uint(v);
    uint32 r = (u + 0x7fffu + ((u >> 16) & 1u)) >> 16;
    *back = __uint_as_float(r << 16);
    return (short)r;
}

// ---- prep: x -> xb (row-major packed bf16); weights -> hi/lo planes ----
__global__ void k_prep(const float* __restrict__ x, uint32* __restrict__ xb,
                       long n4,
                       const float* __restrict__ W1l, const float* __restrict__ W1r,
                       const float* __restrict__ W2l, const float* __restrict__ W2r,
                       short* __restrict__ W1pH, short* __restrict__ W1pL,
                       short* __restrict__ W2pH, short* __restrict__ W2pL) {
    long i = (long)blockIdx.x * blockDim.x + threadIdx.x;
    float back;
    if (i < n4) {
        float4 v = ((const float4*)x)[i];
        short h0 = rne16(v.x, &back);
        short h1 = rne16(v.y, &back);
        short h2 = rne16(v.z, &back);
        short h3 = rne16(v.w, &back);
        uint2 o;
        o.x = (uint32)(unsigned short)h0 | ((uint32)(unsigned short)h1 << 16);
        o.y = (uint32)(unsigned short)h2 | ((uint32)(unsigned short)h3 << 16);
        ((uint2*)xb)[i] = o;
        return;
    }
    int i2 = (int)(i - n4);
    if (i2 < 32768) {
        int j = i2 >> 8, k = i2 & 255;
        float v = (k < 128) ? W1l[j * 128 + k] : W1r[j * 128 + k - 128];
        float hb;
        short hs = rne16(v, &hb);
        short ls = rne16(v - hb, &back);
        int idx = (k >> 3) * 1024 + j * 8 + (k & 7);
        W1pH[idx] = hs;
        W1pL[idx] = ls;
    } else if (i2 < 32768 + 16384) {
        int i3 = i2 - 32768;
        int j = i3 >> 7, k = i3 & 127;
        float v = (j < 64) ? W2l[j * 128 + k] : W2r[(j - 64) * 128 + k];
        float hb;
        short hs = rne16(v, &hb);
        short ls = rne16(v - hb, &back);
        int idx = (k >> 3) * 1024 + j * 8 + (k & 7);
        W2pH[idx] = hs;
        W2pL[idx] = ls;
    }
}

// ---- bucketed CSR build (R14 form) ----

__global__ void k_bcount(const int* __restrict__ ei, int E, int NB,
                         int* __restrict__ bucket_cnt) {
    __shared__ int hist[1024];
    int t = threadIdx.x;
    for (int i = t; i < NB; i += 256) hist[i] = 0;
    __syncthreads();
    int stride = gridDim.x * 256;
    for (int e = blockIdx.x * 256 + t; e < E; e += stride)
        atomicAdd(&hist[ei[E + e] >> 8], 1);
    __syncthreads();
    for (int i = t; i < NB; i += 256) {
        int c = hist[i];
        if (c) atomicAdd(&bucket_cnt[i], c);
    }
}

__global__ void k_bscan(const int* __restrict__ bucket_cnt, int NB, int E,
                        int* __restrict__ bucket_off, int* __restrict__ bucket_cur) {
    __shared__ int s[1024];
    int t = threadIdx.x;
    int v = (t < NB) ? bucket_cnt[t] : 0;
    s[t] = v;
    __syncthreads();
    for (int o = 1; o < 1024; o <<= 1) {
        int u = (t >= o) ? s[t - o] : 0;
        __syncthreads();
        s[t] += u;
        __syncthreads();
    }
    int ex = s[t] - v;
    if (t < NB) { bucket_off[t] = ex; bucket_cur[t] = ex; }
    if (t == NB - 1) bucket_off[NB] = ex + v;
}

__global__ void k_bscatter(const int* __restrict__ ei, int E, int NB,
                           int* __restrict__ bucket_cur, uint32* __restrict__ eb) {
    __shared__ int hist[1024];
    __shared__ int base[1024];
    int t = threadIdx.x;
    for (int i = t; i < NB; i += 256) hist[i] = 0;
    __syncthreads();
    int stride = gridDim.x * 256;
    for (int e = blockIdx.x * 256 + t; e < E; e += stride)
        atomicAdd(&hist[ei[E + e] >> 8], 1);
    __syncthreads();
    for (int i = t; i < NB; i += 256) {
        int c = hist[i];
        base[i] = c ? atomicAdd(&bucket_cur[i], c) : 0;
        hist[i] = 0;
    }
    __syncthreads();
    for (int e = blockIdx.x * 256 + t; e < E; e += stride) {
        int d = ei[E + e];
        int b = d >> 8;
        int r = atomicAdd(&hist[b], 1);
        eb[base[b] + r] = ((uint32)(d & 255) << 24) | (uint32)ei[e];
    }
}

__global__ void k_bfinal(const uint32* __restrict__ eb,
                         const int* __restrict__ bucket_off,
                         int* __restrict__ row_ptr, int* __restrict__ col,
                         int N, int E) {
    __shared__ int deg[256];
    __shared__ int sc[256];
    __shared__ int cur[256];
    int b = blockIdx.x;
    int t = threadIdx.x;
    int beg = bucket_off[b], end = bucket_off[b + 1];
    deg[t] = 0;
    __syncthreads();
    for (int e = beg + t; e < end; e += 256)
        atomicAdd(&deg[eb[e] >> 24], 1);
    __syncthreads();
    int v = deg[t];
    sc[t] = v;
    __syncthreads();
    for (int o = 1; o < 256; o <<= 1) {
        int u = (t >= o) ? sc[t - o] : 0;
        __syncthreads();
        sc[t] += u;
        __syncthreads();
    }
    int ex = sc[t] - v;
    int node = b * 256 + t;
    if (node < N) row_ptr[node] = beg + ex;
    if (b == gridDim.x - 1 && t == 0) row_ptr[N] = E;
    cur[t] = ex;
    __syncthreads();
    for (int e = beg + t; e < end; e += 256) {
        uint32 u = eb[e];
        int r = atomicAdd(&cur[u >> 24], 1);
        col[beg + r] = (int)(u & 0xFFFFFFu);
    }
}

// ---- fused gather-mean + 2x MFMA GEMM (byte-identical to R17, 99us) ----

__global__ __launch_bounds__(256, 4) void k_fused(
        const int* __restrict__ rp, const int* __restrict__ col,
        const uint32* __restrict__ xb,
        const short* __restrict__ W1pH, const short* __restrict__ W1pL,
        const short* __restrict__ W2pH, const short* __restrict__ W2pL,
        const float* __restrict__ b1, const float* __restrict__ b2,
        unsigned short* __restrict__ hl, float* __restrict__ hr, int N) {
    __shared__ short smH[16 * PSTR];  // mean hi planes; reused for h hi
    __shared__ short smL[16 * PSTR];  // mean lo planes; reused for h lo
    int t = threadIdx.x;
    int w = t >> 6, lane = t & 63;
    int node0 = blockIdx.x * 32;

    // phase A: gather-mean for 8 nodes/wave. rp prefetched via one load.
    int base = node0 + 8 * w;
    int rpi = base + lane;
    if (rpi > N) rpi = N;
    int rpv = rp[rpi];

#define ACC1(a) { s += (f32x2){bf_lo(a), __uint_as_float(a)}; }

    for (int i = 0; i < 8; i++) {
        int lr = 8 * w + i;
        int beg = __builtin_amdgcn_readfirstlane(__shfl(rpv, i));
        int end = __builtin_amdgcn_readfirstlane(__shfl(rpv, i + 1));
        f32x2 s = (f32x2){0.f, 0.f};
        int e = beg;
        for (; e + 8 <= end; e += 8) {
            int c0 = col[e + 0], c1 = col[e + 1], c2 = col[e + 2], c3 = col[e + 3];
            int c4 = col[e + 4], c5 = col[e + 5], c6 = col[e + 6], c7 = col[e + 7];
            uint32 a0 = xb[(size_t)c0 * 64 + lane];
            uint32 a1 = xb[(size_t)c1 * 64 + lane];
            uint32 a2 = xb[(size_t)c2 * 64 + lane];
            uint32 a3 = xb[(size_t)c3 * 64 + lane];
            uint32 a4 = xb[(size_t)c4 * 64 + lane];
            uint32 a5 = xb[(size_t)c5 * 64 + lane];
            uint32 a6 = xb[(size_t)c6 * 64 + lane];
            uint32 a7 = xb[(size_t)c7 * 64 + lane];
            ACC1(a0); ACC1(a1); ACC1(a2); ACC1(a3);
            ACC1(a4); ACC1(a5); ACC1(a6); ACC1(a7);
        }
        for (; e + 4 <= end; e += 4) {
            int c0 = col[e + 0], c1 = col[e + 1], c2 = col[e + 2], c3 = col[e + 3];
            uint32 a0 = xb[(size_t)c0 * 64 + lane];
            uint32 a1 = xb[(size_t)c1 * 64 + lane];
            uint32 a2 = xb[(size_t)c2 * 64 + lane];
            uint32 a3 = xb[(size_t)c3 * 64 + lane];
            ACC1(a0); ACC1(a1); ACC1(a2); ACC1(a3);
        }
        for (; e < end; e++) {
            uint32 a0 = xb[(size_t)col[e] * 64 + lane];
            ACC1(a0);
        }
        // epilogue: lane l -> plane l>>2, node lr, shorts 2(l&3)..+1
        float inv = 1.0f / (float)max(end - beg, 1);
        float m0 = s.x * inv, m1 = s.y * inv;
        float b_;
        short h0 = rne16(m0, &b_);
        float bk0 = b_;
        short l0 = rne16(m0 - bk0, &b_);
        short h1 = rne16(m1, &b_);
        float bk1 = b_;
        short l1 = rne16(m1 - bk1, &b_);
        uint32 H = (uint32)(unsigned short)h0 | ((uint32)(unsigned short)h1 << 16);
        uint32 L = (uint32)(unsigned short)l0 | ((uint32)(unsigned short)l1 << 16);
        int idx = (lane >> 2) * PSTR + lr * 8 + 2 * (lane & 3);
        *(uint32*)&smH[idx] = H;
        *(uint32*)&smL[idx] = L;
    }
#undef ACC1
    __syncthreads();

    // phase B: GEMM1 (mean hi/lo from LDS + x hi direct from xb), tile jt=w
    int m = lane & 31, hh = lane >> 5;
    int mynode = node0 + m;
    const short* xbs = (const short*)xb;  // row = 128 shorts (feature order)
    f32x16 acc;
#pragma unroll
    for (int r = 0; r < 16; r++) acc[r] = 0.f;
#pragma unroll
    for (int kc = 0; kc < 8; kc++) {
        int c = 2 * kc + hh;
        bf16x8 bH = *(const bf16x8*)&smH[c * PSTR + m * 8];
        bf16x8 bL = *(const bf16x8*)&smL[c * PSTR + m * 8];
        bf16x8 xH = *(const bf16x8*)(xbs + (size_t)mynode * 128 + c * 8);
        bf16x8 aH1 = *(const bf16x8*)(W1pH + c * 1024 + (32 * w + m) * 8);
        bf16x8 aL1 = *(const bf16x8*)(W1pL + c * 1024 + (32 * w + m) * 8);
        bf16x8 aH2 = *(const bf16x8*)(W1pH + (16 + c) * 1024 + (32 * w + m) * 8);
        bf16x8 aL2 = *(const bf16x8*)(W1pL + (16 + c) * 1024 + (32 * w + m) * 8);
        acc = __builtin_amdgcn_mfma_f32_32x32x16_bf16(aH1, bH, acc, 0, 0, 0);
        acc = __builtin_amdgcn_mfma_f32_32x32x16_bf16(aL1, bH, acc, 0, 0, 0);
        acc = __builtin_amdgcn_mfma_f32_32x32x16_bf16(aH1, bL, acc, 0, 0, 0);
        acc = __builtin_amdgcn_mfma_f32_32x32x16_bf16(aH2, xH, acc, 0, 0, 0);
        acc = __builtin_amdgcn_mfma_f32_32x32x16_bf16(aL2, xH, acc, 0, 0, 0);
    }

    // epilogue 1: relu + b1 -> h (hi/lo) in regs
    uint2 oh[4], ol[4];
#pragma unroll
    for (int rg = 0; rg < 4; rg++) {
        int j0 = 32 * w + 8 * rg + 4 * hh;
        float4 bv = *(const float4*)(b1 + j0);
        float bb[4] = {bv.x, bv.y, bv.z, bv.w};
        short hs[4], ls[4];
#pragma unroll
        for (int q = 0; q < 4; q++) {
            float v = fmaxf(acc[4 * rg + q] + bb[q], 0.f);
            float back;
            hs[q] = rne16(v, &back);
            ls[q] = rne16(v - back, &back);
        }
        oh[rg].x = (uint32)(unsigned short)hs[0] | ((uint32)(unsigned short)hs[1] << 16);
        oh[rg].y = (uint32)(unsigned short)hs[2] | ((uint32)(unsigned short)hs[3] << 16);
        ol[rg].x = (uint32)(unsigned short)ls[0] | ((uint32)(unsigned short)ls[1] << 16);
        ol[rg].y = (uint32)(unsigned short)ls[2] | ((uint32)(unsigned short)ls[3] << 16);
    }
    __syncthreads();  // all waves done reading mean planes
#pragma unroll
    for (int rg = 0; rg < 4; rg++) {
        int idx = (4 * w + rg) * PSTR + m * 8 + 4 * hh;  // plane j>>3 = 4w+rg
        *(uint2*)&smH[idx] = oh[rg];
        *(uint2*)&smL[idx] = ol[rg];
    }
    __syncthreads();

    // GEMM2: B-fragments from LDS h planes, tile jt=w
#pragma unroll
    for (int r = 0; r < 16; r++) acc[r] = 0.f;
#pragma unroll
    for (int kc = 0; kc < 8; kc++) {
        int c = 2 * kc + hh;
        bf16x8 bH = *(const bf16x8*)&smH[c * PSTR + m * 8];
        bf16x8 bL = *(const bf16x8*)&smL[c * PSTR + m * 8];
        bf16x8 aH = *(const bf16x8*)(W2pH + c * 1024 + (32 * w + m) * 8);
        bf16x8 aL = *(const bf16x8*)(W2pL + c * 1024 + (32 * w + m) * 8);
        acc = __builtin_amdgcn_mfma_f32_32x32x16_bf16(aH, bH, acc, 0, 0, 0);
        acc = __builtin_amdgcn_mfma_f32_32x32x16_bf16(aL, bH, acc, 0, 0, 0);
        acc = __builtin_amdgcn_mfma_f32_32x32x16_bf16(aH, bL, acc, 0, 0, 0);
    }
    if (mynode >= N) return;
    if (w < 2) {
        // waves 0,1: cols 0..63 = h @ W2l^T -> hl (bf16)
#pragma unroll
        for (int rg = 0; rg < 4; rg++) {
            int j0 = 32 * w + 8 * rg + 4 * hh;
            uint2 o;
            o.x = pack_bf16_rne(acc[4 * rg + 0], acc[4 * rg + 1]);
            o.y = pack_bf16_rne(acc[4 * rg + 2], acc[4 * rg + 3]);
            *(uint2*)&hl[(size_t)mynode * 64 + j0] = o;
        }
    } else {
        // waves 2,3: cols 64..127 = h @ W2r^T + b2 -> hr (fp32)
#pragma unroll
        for (int rg = 0; rg < 4; rg++) {
            int j0 = 32 * (w - 2) + 8 * rg + 4 * hh;
            float4 bv = *(const float4*)(b2 + j0);
            float4 o;
            o.x = acc[4 * rg + 0] + bv.x;
            o.y = acc[4 * rg + 1] + bv.y;
            o.z = acc[4 * rg + 2] + bv.z;
            o.w = acc[4 * rg + 3] + bv.w;
            *(float4*)&hr[(size_t)mynode * 64 + j0] = o;
        }
    }
}

// ---- aggregation 2 (R19): TWO nodes per wave (half-wave each). Within a
// half: g=4 groups x f=8 lanes, uint4 row slice (8 lanes x 16B = 128B row),
// uint4 col loads -> 16 edges/iter/node, 4 rows in flight per lane. ----

__global__ void k_agg_out(const int* __restrict__ rp, const int* __restrict__ col,
                          const unsigned short* __restrict__ hl,
                          const float* __restrict__ hr,
                          float* __restrict__ out, int N) {
    int node = blockIdx.x * 8 + (threadIdx.x >> 5);  // half-wave per node
    if (node >= N) return;
    int h = threadIdx.x & 31;
    int g = h >> 3;   // 4 groups
    int f = h & 7;    // 8 lanes: features [8f, 8f+8)
    int beg = rp[node], end = rp[node + 1];
    const uint4* hl4 = (const uint4*)hl;  // row = 8 uint4 (128B)
    f32x2 sA[4];
#pragma unroll
    for (int j = 0; j < 4; j++) sA[j] = (f32x2){0.f, 0.f};

#define ACC_MSK(v)                                          \
    { sA[0] += (f32x2){bf_lo(v.x), bf_hi(v.x)};             \
      sA[1] += (f32x2){bf_lo(v.y), bf_hi(v.y)};             \
      sA[2] += (f32x2){bf_lo(v.z), bf_hi(v.z)};             \
      sA[3] += (f32x2){bf_lo(v.w), bf_hi(v.w)}; }

    int e = beg;
    for (; e + 16 <= end; e += 16) {
        uint4 cv = *(const uint4*)(col + e + 4 * g);
        uint4 v0 = hl4[(size_t)cv.x * 8 + f];
        uint4 v1 = hl4[(size_t)cv.y * 8 + f];
        uint4 v2 = hl4[(size_t)cv.z * 8 + f];
        uint4 v3 = hl4[(size_t)cv.w * 8 + f];
        ACC_MSK(v0); ACC_MSK(v1); ACC_MSK(v2); ACC_MSK(v3);
    }
    for (; e + 8 <= end; e += 8) {
        uint2 cv = *(const uint2*)(col + e + 2 * g);
        uint4 v0 = hl4[(size_t)cv.x * 8 + f];
        uint4 v1 = hl4[(size_t)cv.y * 8 + f];
        ACC_MSK(v0); ACC_MSK(v1);
    }
    int rem = end - e;
    if (2 * g < rem) {
        uint4 v0 = hl4[(size_t)col[e + 2 * g] * 8 + f];
        ACC_MSK(v0);
    }
    if (2 * g + 1 < rem) {
        uint4 v0 = hl4[(size_t)col[e + 2 * g + 1] * 8 + f];
        ACC_MSK(v0);
    }
#undef ACC_MSK
    // reduce over the 4 groups (stays within the 32-lane half)
#pragma unroll
    for (int p = 0; p < 4; p++) {
        sA[p].x += __shfl_xor(sA[p].x, 8);
        sA[p].y += __shfl_xor(sA[p].y, 8);
        sA[p].x += __shfl_xor(sA[p].x, 16);
        sA[p].y += __shfl_xor(sA[p].y, 16);
    }
    if (g == 0) {
        float inv = 1.0f / (float)max(end - beg, 1);
        const float* hrp = hr + (size_t)node * 64 + f * 8;
        float4 h0 = *(const float4*)(hrp);
        float4 h1 = *(const float4*)(hrp + 4);
        float4 o0, o1;
        o0.x = sA[0].x * inv + h0.x;
        o0.y = sA[0].y * inv + h0.y;
        o0.z = sA[1].x * inv + h0.z;
        o0.w = sA[1].y * inv + h0.w;
        o1.x = sA[2].x * inv + h1.x;
        o1.y = sA[2].y * inv + h1.y;
        o1.z = sA[3].x * inv + h1.z;
        o1.w = sA[3].y * inv + h1.w;
        float* op = out + (size_t)node * 64 + f * 8;
        *(float4*)(op) = o0;
        *(float4*)(op + 4) = o1;
    }
}

extern "C" void kernel_launch(void* const* d_in, const int* in_sizes, int n_in,
                              void* d_out, int out_size, void* d_ws, size_t ws_size,
                              hipStream_t stream) {
    const float* x   = (const float*)d_in[0];
    const float* W1l = (const float*)d_in[1];
    const float* W1r = (const float*)d_in[2];
    const float* b1  = (const float*)d_in[3];
    const float* W2l = (const float*)d_in[4];
    const float* W2r = (const float*)d_in[5];
    const float* b2  = (const float*)d_in[6];
    const int*   ei  = (const int*)d_in[7];
    int N = in_sizes[0] / 128;
    int E = in_sizes[7] / 2;
    int NB = (N + 255) >> 8;
    int mb = (N + 31) / 32;
    int Np = ((N + 127) / 128) * 128;  // padded node count
    float* out = (float*)d_out;

    char* w = (char*)d_ws;
    size_t off = 0;
    auto alloc = [&](size_t bytes) -> char* {
        char* p = w + off;
        off += (bytes + 255) & ~(size_t)255;
        return p;
    };
    int*   row_ptr = (int*)alloc((size_t)(N + 1) * 4);
    int*   bcnt    = (int*)alloc((size_t)(NB + 1) * 4);
    int*   boff    = (int*)alloc((size_t)(NB + 1) * 4);
    int*   bcur    = (int*)alloc((size_t)(NB + 1) * 4);
    short* W1pH    = (short*)alloc(32768 * 2);
    short* W1pL    = (short*)alloc(32768 * 2);
    short* W2pH    = (short*)alloc(16384 * 2);
    short* W2pL    = (short*)alloc(16384 * 2);
    int*   col     = (int*)alloc((size_t)E * 4);
    uint32* xb     = (uint32*)alloc((size_t)Np * 64 * 4);   // 25.6 MB
    float*  hr     = (float*)alloc((size_t)Np * 64 * 4);    // 25.6 MB
    unsigned short* hl = (unsigned short*)alloc((size_t)N * 64 * 2);  // 12.8 MB
    // alias (lifetime-disjoint): eb dead after k_bfinal; hl written by k_fused
    uint32* eb = (uint32*)hl;

    hipMemsetAsync(bcnt, 0, (size_t)NB * 4, stream);
    long n4 = (long)N * 32;
    long prep_items = n4 + 32768 + 16384;
    k_prep<<<(int)((prep_items + 255) / 256), 256, 0, stream>>>(
        x, xb, n4, W1l, W1r, W2l, W2r, W1pH, W1pL, W2pH, W2pL);
    k_bcount<<<256, 256, 0, stream>>>(ei, E, NB, bcnt);
    k_bscan<<<1, 1024, 0, stream>>>(bcnt, NB, E, boff, bcur);
    k_bscatter<<<128, 256, 0, stream>>>(ei, E, NB, bcur, eb);
    k_bfinal<<<NB, 256, 0, stream>>>(eb, boff, row_ptr, col, N, E);

    k_fused<<<mb, 256, 0, stream>>>(row_ptr, col, xb, W1pH, W1pL, W2pH, W2pL,
                                    b1, b2, hl, hr, N);
    int ab = (N + 7) / 8;
    k_agg_out<<<ab, 256, 0, stream>>>(row_ptr, col, hl, hr, out, N);
}